// Round 9
// baseline (185.752 us; speedup 1.0000x reference)
//
#include <hip/hip_runtime.h>
#include <hip/hip_bf16.h>

#define N_NODES 100000
#define N_EDGES 1600000
#define D 128
#define NBUCK 782        // ceil(100000/128) buckets of 128 rows
#define G 320            // partition blocks
#define EPB 5000         // edges per partition block (320*5000 = 1.6M)
#define CAPG 16          // slots per (bucket, block) window = 128B, line-aligned
#define WSLOT (G * CAPG) // 5120 slots per bucket in tmp
#define EBCAP 2816       // LDS staging capacity in k_sort
#define OCAP 8192        // overflow capacity

typedef short  s8v  __attribute__((ext_vector_type(8)));
typedef float  f4v  __attribute__((ext_vector_type(4)));
typedef float  f4n  __attribute__((ext_vector_type(4)));
typedef int    i2n  __attribute__((ext_vector_type(2)));
typedef uint   u2n  __attribute__((ext_vector_type(2)));

__device__ __forceinline__ ushort f2bf(float f) {
    uint u = __float_as_uint(f);
    return (ushort)((u + 0x7FFFu + ((u >> 16) & 1u)) >> 16);
}
__device__ __forceinline__ float bflo(uint u) { return __uint_as_float(u << 16); }
__device__ __forceinline__ float bfhi(uint u) { return __uint_as_float(u & 0xFFFF0000u); }

// ---------------------------------------------------------------------------
// wt[n][k] = bf16(w[k][n]); zeroes overflow cursor
// ---------------------------------------------------------------------------
__global__ __launch_bounds__(256) void k_wt(const float* __restrict__ w,
                                            ushort* __restrict__ wt,
                                            int* __restrict__ ocur) {
    int i = blockIdx.x * 256 + threadIdx.x;
    if (i == 0) *ocur = 0;
    if (i < D * D) {
        int k = i >> 7, n = i & 127;
        wt[n * D + k] = f2bf(w[i]);
    }
}

// ---------------------------------------------------------------------------
// supb = bf16( X @ W )  via MFMA 16x16x32 bf16  (validated; X reads nt)
// ---------------------------------------------------------------------------
__global__ __launch_bounds__(256, 2) void k_gemm(const float* __restrict__ x,
                                                 const ushort* __restrict__ wt,
                                                 ushort* __restrict__ supb) {
    __shared__ int4 Bl4[2048];            // 32 KB
    char* Bl = (char*)Bl4;

    const int t    = threadIdx.x;
    const int lane = t & 63;
    const int w    = t >> 6;
    const int row0 = blockIdx.x * 128;

    const int4* g = (const int4*)wt;
    #pragma unroll
    for (int i = 0; i < 8; ++i) {
        int idx = t + i * 256;
        int n = idx >> 4, c = idx & 15;
        *(int4*)(Bl + ((n * 256 + c * 16) ^ ((n & 7) << 4))) = g[idx];
    }
    __syncthreads();

    f4v acc[2][8] = {};
    const int arow = row0 + w * 32 + (lane & 15);
    const int kb   = (lane >> 4) * 8;

    #pragma unroll
    for (int ks = 0; ks < 4; ++ks) {
        s8v a[2];
        #pragma unroll
        for (int m = 0; m < 2; ++m) {
            int r = arow + m * 16;
            f4n f0 = {0.f, 0.f, 0.f, 0.f};
            f4n f1 = {0.f, 0.f, 0.f, 0.f};
            if (r < N_NODES) {
                const f4n* p = (const f4n*)(x + (size_t)r * D + ks * 32 + kb);
                f0 = __builtin_nontemporal_load(p);
                f1 = __builtin_nontemporal_load(p + 1);
            }
            s8v av;
            av[0] = (short)f2bf(f0[0]); av[1] = (short)f2bf(f0[1]);
            av[2] = (short)f2bf(f0[2]); av[3] = (short)f2bf(f0[3]);
            av[4] = (short)f2bf(f1[0]); av[5] = (short)f2bf(f1[1]);
            av[6] = (short)f2bf(f1[2]); av[7] = (short)f2bf(f1[3]);
            a[m] = av;
        }
        #pragma unroll
        for (int n = 0; n < 8; ++n) {
            int brow = n * 16 + (lane & 15);
            s8v b = *(s8v*)(Bl + ((brow * 256 + (ks * 32 + kb) * 2) ^ ((brow & 7) << 4)));
            acc[0][n] = __builtin_amdgcn_mfma_f32_16x16x32_bf16(a[0], b, acc[0][n], 0, 0, 0);
            acc[1][n] = __builtin_amdgcn_mfma_f32_16x16x32_bf16(a[1], b, acc[1][n], 0, 0, 0);
        }
    }

    __syncthreads();
    char* E = Bl + w * 8192;
    #pragma unroll
    for (int m = 0; m < 2; ++m)
        #pragma unroll
        for (int n = 0; n < 8; ++n)
            #pragma unroll
            for (int r = 0; r < 4; ++r) {
                int rl  = m * 16 + ((lane >> 4) << 2) + r;
                int col = n * 16 + (lane & 15);
                *(ushort*)(E + ((rl * 256 + col * 2) ^ ((rl & 7) << 4))) =
                    f2bf(acc[m][n][r]);
            }
    __syncthreads();
    #pragma unroll
    for (int i = 0; i < 8; ++i) {
        int idx = lane + i * 64;
        int rl = idx >> 4, c = idx & 15;
        int4 v = *(int4*)(E + ((rl * 256 + c * 16) ^ ((rl & 7) << 4)));
        int grow = row0 + w * 32 + rl;
        if (grow < N_NODES)
            *(int4*)((char*)supb + (size_t)grow * 256 + c * 16) = v;
    }
}

// ---------------------------------------------------------------------------
// Block-private partition (validated round 8); edge-stream reads nt.
// ---------------------------------------------------------------------------
__global__ __launch_bounds__(512) void k_part(const int* __restrict__ er,
                                              const int* __restrict__ ec,
                                              const float* __restrict__ ev,
                                              int2* __restrict__ tmp,
                                              int* __restrict__ counts,
                                              int* __restrict__ ocur,
                                              int4* __restrict__ ovf) {
    __shared__ int cur[NBUCK];
    const int tx = (int)threadIdx.x;
    const int g  = blockIdx.x;
    for (int i = tx; i < NBUCK; i += 512) cur[i] = 0;
    __syncthreads();

    const int base = g * EPB;
    for (int i = tx; i < EPB; i += 512) {
        int e = base + i;
        int   r = __builtin_nontemporal_load(er + e);
        int   c = __builtin_nontemporal_load(ec + e);
        float v = __builtin_nontemporal_load(ev + e);
        int b = r >> 7;
        int p = atomicAdd(&cur[b], 1);
        if (p < CAPG) {
            tmp[(size_t)b * WSLOT + g * CAPG + p] =
                make_int2(((r & 127) << 17) | c, __float_as_int(v));
        } else {
            int o = atomicAdd(ocur, 1);
            if (o < OCAP) ovf[o] = make_int4(r, c, __float_as_int(v), 0);
        }
    }
    __syncthreads();
    for (int i = tx; i < NBUCK; i += 512) {
        int n = cur[i];
        counts[g * NBUCK + i] = (n > CAPG) ? CAPG : n;
    }
}

// ---------------------------------------------------------------------------
// Per-bucket CSR build, in-place (validated round 8); window reads nt.
// ---------------------------------------------------------------------------
__global__ __launch_bounds__(320) void k_sort(int2* __restrict__ tmp,
                                              const int* __restrict__ counts,
                                              int2* __restrict__ rowrg,
                                              int* __restrict__ ocur,
                                              int4* __restrict__ ovf) {
    __shared__ int wn[G];
    __shared__ int wincl[G];
    __shared__ int hist[128], ex[128], cur[128];
    __shared__ int2 eb[EBCAP];
    const int tx = (int)threadIdx.x;
    const int b  = blockIdx.x;
    const int r0 = b << 7;

    int n = counts[tx * NBUCK + b];
    wn[tx] = n;
    wincl[tx] = n;
    if (tx < 128) { hist[tx] = 0; cur[tx] = 0; }
    __syncthreads();

    for (int off = 1; off < G; off <<= 1) {
        int t = (tx >= off) ? wincl[tx - off] : 0;
        __syncthreads();
        wincl[tx] += t;
        __syncthreads();
    }
    const int cnt0 = wincl[G - 1];

    {
        int o = wincl[tx] - wn[tx];
        const i2n* win = (const i2n*)(tmp + ((size_t)b * G + tx) * CAPG);
        for (int k = 0; k < wn[tx]; ++k) {
            int idx = o + k;
            i2n tv = __builtin_nontemporal_load(win + k);
            int2 t = make_int2(tv[0], tv[1]);
            if (idx < EBCAP) {
                eb[idx] = t;
            } else {
                int oo = atomicAdd(ocur, 1);
                if (oo < OCAP)
                    ovf[oo] = make_int4(r0 + (t.x >> 17), t.x & 0x1FFFF, t.y, 0);
            }
        }
    }
    __syncthreads();
    const int cnt = (cnt0 > EBCAP) ? EBCAP : cnt0;

    for (int i = tx; i < cnt; i += 320)
        atomicAdd(&hist[eb[i].x >> 17], 1);
    __syncthreads();

    int hv = (tx < 128) ? hist[tx] : 0;
    if (tx < 128) ex[tx] = hv;
    __syncthreads();
    for (int off = 1; off < 128; off <<= 1) {
        int t = 0;
        if (tx < 128 && tx >= off) t = ex[tx - off];
        __syncthreads();
        if (tx < 128) ex[tx] += t;
        __syncthreads();
    }
    if (tx < 128) {
        int incl = ex[tx];
        int e0   = incl - hv;
        if (r0 + tx < N_NODES)
            rowrg[r0 + tx] = make_int2(b * WSLOT + e0, b * WSLOT + incl);
        ex[tx] = e0;
    }
    __syncthreads();

    int2* dst = tmp + (size_t)b * WSLOT;
    for (int i = tx; i < cnt; i += 320) {
        int2 t = eb[i];
        int lr = t.x >> 17;
        int p  = ex[lr] + atomicAdd(&cur[lr], 1);
        dst[p] = make_int2(t.x & 0x1FFFF, t.y);
    }
}

// ---------------------------------------------------------------------------
// CSR SpMM: one wave per row; half-wave per edge; 16 edges/iter (8 gathers
// in flight per lane); nt loads for scv, nt stores for out (no L2 pollution
// of supb). Fold via __shfl_xor(32); float4 store with bias.
// ---------------------------------------------------------------------------
__global__ __launch_bounds__(256) void k_spmm(const ushort* __restrict__ supb,
                                              const int2* __restrict__ rowrg,
                                              const int2* __restrict__ scv,
                                              const float* __restrict__ bias,
                                              float* __restrict__ out) {
    const int row = blockIdx.x * 4 + (threadIdx.x >> 6);
    if (row >= N_NODES) return;
    const int lane = threadIdx.x & 63;
    const int sub  = lane >> 5;
    const int sl   = lane & 31;

    const int2 rg = rowrg[row];
    int j = rg.x;
    const int end = rg.y;
    const uint2* S = (const uint2*)supb;
    const i2n* SCV = (const i2n*)scv;

    float ax = 0.f, ay = 0.f, az = 0.f, aw = 0.f;

    // 16 edges per iteration (8 per half-wave): single latency window for a
    // mean-sized (16-edge) row
    for (; j + 15 < end; j += 16) {
        i2n e0 = __builtin_nontemporal_load(SCV + j + sub);
        i2n e1 = __builtin_nontemporal_load(SCV + j + 2 + sub);
        i2n e2 = __builtin_nontemporal_load(SCV + j + 4 + sub);
        i2n e3 = __builtin_nontemporal_load(SCV + j + 6 + sub);
        i2n e4 = __builtin_nontemporal_load(SCV + j + 8 + sub);
        i2n e5 = __builtin_nontemporal_load(SCV + j + 10 + sub);
        i2n e6 = __builtin_nontemporal_load(SCV + j + 12 + sub);
        i2n e7 = __builtin_nontemporal_load(SCV + j + 14 + sub);
        uint2 s0 = S[(size_t)e0[0] * 32 + sl];
        uint2 s1 = S[(size_t)e1[0] * 32 + sl];
        uint2 s2 = S[(size_t)e2[0] * 32 + sl];
        uint2 s3 = S[(size_t)e3[0] * 32 + sl];
        uint2 s4 = S[(size_t)e4[0] * 32 + sl];
        uint2 s5 = S[(size_t)e5[0] * 32 + sl];
        uint2 s6 = S[(size_t)e6[0] * 32 + sl];
        uint2 s7 = S[(size_t)e7[0] * 32 + sl];
        float v0 = __int_as_float(e0[1]), v1 = __int_as_float(e1[1]);
        float v2 = __int_as_float(e2[1]), v3 = __int_as_float(e3[1]);
        float v4 = __int_as_float(e4[1]), v5 = __int_as_float(e5[1]);
        float v6 = __int_as_float(e6[1]), v7 = __int_as_float(e7[1]);
        ax += v0 * bflo(s0.x) + v1 * bflo(s1.x) + v2 * bflo(s2.x) + v3 * bflo(s3.x)
            + v4 * bflo(s4.x) + v5 * bflo(s5.x) + v6 * bflo(s6.x) + v7 * bflo(s7.x);
        ay += v0 * bfhi(s0.x) + v1 * bfhi(s1.x) + v2 * bfhi(s2.x) + v3 * bfhi(s3.x)
            + v4 * bfhi(s4.x) + v5 * bfhi(s5.x) + v6 * bfhi(s6.x) + v7 * bfhi(s7.x);
        az += v0 * bflo(s0.y) + v1 * bflo(s1.y) + v2 * bflo(s2.y) + v3 * bflo(s3.y)
            + v4 * bflo(s4.y) + v5 * bflo(s5.y) + v6 * bflo(s6.y) + v7 * bflo(s7.y);
        aw += v0 * bfhi(s0.y) + v1 * bfhi(s1.y) + v2 * bfhi(s2.y) + v3 * bfhi(s3.y)
            + v4 * bfhi(s4.y) + v5 * bfhi(s5.y) + v6 * bfhi(s6.y) + v7 * bfhi(s7.y);
    }
    for (; j + 7 < end; j += 8) {
        i2n e0 = __builtin_nontemporal_load(SCV + j + sub);
        i2n e1 = __builtin_nontemporal_load(SCV + j + 2 + sub);
        i2n e2 = __builtin_nontemporal_load(SCV + j + 4 + sub);
        i2n e3 = __builtin_nontemporal_load(SCV + j + 6 + sub);
        uint2 s0 = S[(size_t)e0[0] * 32 + sl];
        uint2 s1 = S[(size_t)e1[0] * 32 + sl];
        uint2 s2 = S[(size_t)e2[0] * 32 + sl];
        uint2 s3 = S[(size_t)e3[0] * 32 + sl];
        float v0 = __int_as_float(e0[1]), v1 = __int_as_float(e1[1]);
        float v2 = __int_as_float(e2[1]), v3 = __int_as_float(e3[1]);
        ax += v0 * bflo(s0.x) + v1 * bflo(s1.x) + v2 * bflo(s2.x) + v3 * bflo(s3.x);
        ay += v0 * bfhi(s0.x) + v1 * bfhi(s1.x) + v2 * bfhi(s2.x) + v3 * bfhi(s3.x);
        az += v0 * bflo(s0.y) + v1 * bflo(s1.y) + v2 * bflo(s2.y) + v3 * bflo(s3.y);
        aw += v0 * bfhi(s0.y) + v1 * bfhi(s1.y) + v2 * bfhi(s2.y) + v3 * bfhi(s3.y);
    }
    for (; j < end; j += 2) {
        int jj = j + sub;
        if (jj > end - 1) jj = end - 1;
        int2 e = scv[jj];
        float v = (j + sub < end) ? __int_as_float(e.y) : 0.f;
        uint2 s = S[(size_t)e.x * 32 + sl];
        ax += v * bflo(s.x);
        ay += v * bfhi(s.x);
        az += v * bflo(s.y);
        aw += v * bfhi(s.y);
    }

    ax += __shfl_xor(ax, 32);
    ay += __shfl_xor(ay, 32);
    az += __shfl_xor(az, 32);
    aw += __shfl_xor(aw, 32);

    if (sub == 0) {
        f4n bb = *(const f4n*)(bias + 4 * sl);
        f4n o = {ax + bb[0], ay + bb[1], az + bb[2], aw + bb[3]};
        __builtin_nontemporal_store(o, (f4n*)(out + (size_t)row * D + 4 * sl));
    }
}

// ---------------------------------------------------------------------------
// Overflow cleanup (statistically ~100 edges)
// ---------------------------------------------------------------------------
__global__ __launch_bounds__(256) void k_ofl(const ushort* __restrict__ supb,
                                             const int4* __restrict__ ovf,
                                             const int* __restrict__ ocur,
                                             float* __restrict__ out) {
    int n = *ocur;
    if (n > OCAP) n = OCAP;
    const int lane = threadIdx.x & 63;
    const uint* S = (const uint*)supb;
    for (int e = (blockIdx.x * 256 + threadIdx.x) >> 6; e < n; e += 64) {
        int4 rec = ovf[e];
        uint s = S[(size_t)rec.y * 64 + lane];
        float v = __int_as_float(rec.z);
        atomicAdd(&out[(size_t)rec.x * D + 2 * lane],     v * bflo(s));
        atomicAdd(&out[(size_t)rec.x * D + 2 * lane + 1], v * bfhi(s));
    }
}

extern "C" void kernel_launch(void* const* d_in, const int* in_sizes, int n_in,
                              void* d_out, int out_size, void* d_ws, size_t ws_size,
                              hipStream_t stream) {
    const float* x    = (const float*)d_in[0];
    const float* w    = (const float*)d_in[1];
    const float* bias = (const float*)d_in[2];
    const float* ev   = (const float*)d_in[3];
    const int*   er   = (const int*)d_in[4];
    const int*   ec   = (const int*)d_in[5];
    float* out = (float*)d_out;

    // workspace layout (16B aligned), ~59.6 MB
    char* ws = (char*)d_ws;
    ushort* supb   = (ushort*)(ws);                 // 25,600,000
    ushort* wt     = (ushort*)(ws + 25600000);      //     32,768
    int*    counts = (int*)   (ws + 25632768);      //  1,000,960
    int*    ocur   = (int*)   (ws + 26633728);      //         64
    int4*   ovf    = (int4*)  (ws + 26633792);      //    131,072
    int2*   tmp    = (int2*)  (ws + 26764864);      // 32,030,720
    int2*   rowrg  = (int2*)  (ws + 58795584);      //    800,000

    // order: edge pipeline first, gemm last before spmm (supb stays L2/L3-hot)
    k_wt  <<<64, 256, 0, stream>>>(w, wt, ocur);
    k_part<<<G, 512, 0, stream>>>(er, ec, ev, tmp, counts, ocur, ovf);
    k_sort<<<NBUCK, 320, 0, stream>>>(tmp, counts, rowrg, ocur, ovf);
    k_gemm<<<(N_NODES + 127) / 128, 256, 0, stream>>>(x, wt, supb);

    k_spmm<<<(N_NODES + 3) / 4, 256, 0, stream>>>(supb, rowrg, tmp, bias, out);
    k_ofl <<<16, 256, 0, stream>>>(supb, ovf, ocur, out);
}

// Round 10
// 144.095 us; speedup vs baseline: 1.2891x; 1.2891x over previous
//
#include <hip/hip_runtime.h>
#include <hip/hip_bf16.h>

#define N_NODES 100000
#define N_EDGES 1600000
#define D 128
#define NBUCK 782        // ceil(100000/128) buckets of 128 rows
#define G 320            // partition blocks
#define EPB 5000         // edges per partition block (320*5000 = 1.6M)
#define CAPG 16          // slots per (bucket, block) window = 128B, line-aligned
#define WSLOT (G * CAPG) // 5120 slots per bucket in tmp
#define EBCAP 2816       // LDS staging capacity in k_sort
#define OCAP 8192        // overflow capacity

typedef short  s8v  __attribute__((ext_vector_type(8)));
typedef float  f4v  __attribute__((ext_vector_type(4)));

__device__ __forceinline__ ushort f2bf(float f) {
    uint u = __float_as_uint(f);
    return (ushort)((u + 0x7FFFu + ((u >> 16) & 1u)) >> 16);
}
__device__ __forceinline__ float bflo(uint u) { return __uint_as_float(u << 16); }
__device__ __forceinline__ float bfhi(uint u) { return __uint_as_float(u & 0xFFFF0000u); }

// ---------------------------------------------------------------------------
// wt[n][k] = bf16(w[k][n]); zeroes overflow cursor
// ---------------------------------------------------------------------------
__global__ __launch_bounds__(256) void k_wt(const float* __restrict__ w,
                                            ushort* __restrict__ wt,
                                            int* __restrict__ ocur) {
    int i = blockIdx.x * 256 + threadIdx.x;
    if (i == 0) *ocur = 0;
    if (i < D * D) {
        int k = i >> 7, n = i & 127;
        wt[n * D + k] = f2bf(w[i]);
    }
}

// ---------------------------------------------------------------------------
// supb = bf16( X @ W )  via MFMA 16x16x32 bf16  (validated rounds 3/5/7/8)
// ---------------------------------------------------------------------------
__global__ __launch_bounds__(256, 2) void k_gemm(const float* __restrict__ x,
                                                 const ushort* __restrict__ wt,
                                                 ushort* __restrict__ supb) {
    __shared__ int4 Bl4[2048];            // 32 KB
    char* Bl = (char*)Bl4;

    const int t    = threadIdx.x;
    const int lane = t & 63;
    const int w    = t >> 6;
    const int row0 = blockIdx.x * 128;

    const int4* g = (const int4*)wt;
    #pragma unroll
    for (int i = 0; i < 8; ++i) {
        int idx = t + i * 256;
        int n = idx >> 4, c = idx & 15;
        *(int4*)(Bl + ((n * 256 + c * 16) ^ ((n & 7) << 4))) = g[idx];
    }
    __syncthreads();

    f4v acc[2][8] = {};
    const int arow = row0 + w * 32 + (lane & 15);
    const int kb   = (lane >> 4) * 8;

    #pragma unroll
    for (int ks = 0; ks < 4; ++ks) {
        s8v a[2];
        #pragma unroll
        for (int m = 0; m < 2; ++m) {
            int r = arow + m * 16;
            float4 f0 = make_float4(0.f, 0.f, 0.f, 0.f);
            float4 f1 = make_float4(0.f, 0.f, 0.f, 0.f);
            if (r < N_NODES) {
                const float4* p = (const float4*)(x + (size_t)r * D + ks * 32 + kb);
                f0 = p[0];
                f1 = p[1];
            }
            s8v av;
            av[0] = (short)f2bf(f0.x); av[1] = (short)f2bf(f0.y);
            av[2] = (short)f2bf(f0.z); av[3] = (short)f2bf(f0.w);
            av[4] = (short)f2bf(f1.x); av[5] = (short)f2bf(f1.y);
            av[6] = (short)f2bf(f1.z); av[7] = (short)f2bf(f1.w);
            a[m] = av;
        }
        #pragma unroll
        for (int n = 0; n < 8; ++n) {
            int brow = n * 16 + (lane & 15);
            s8v b = *(s8v*)(Bl + ((brow * 256 + (ks * 32 + kb) * 2) ^ ((brow & 7) << 4)));
            acc[0][n] = __builtin_amdgcn_mfma_f32_16x16x32_bf16(a[0], b, acc[0][n], 0, 0, 0);
            acc[1][n] = __builtin_amdgcn_mfma_f32_16x16x32_bf16(a[1], b, acc[1][n], 0, 0, 0);
        }
    }

    __syncthreads();
    char* E = Bl + w * 8192;
    #pragma unroll
    for (int m = 0; m < 2; ++m)
        #pragma unroll
        for (int n = 0; n < 8; ++n)
            #pragma unroll
            for (int r = 0; r < 4; ++r) {
                int rl  = m * 16 + ((lane >> 4) << 2) + r;
                int col = n * 16 + (lane & 15);
                *(ushort*)(E + ((rl * 256 + col * 2) ^ ((rl & 7) << 4))) =
                    f2bf(acc[m][n][r]);
            }
    __syncthreads();
    #pragma unroll
    for (int i = 0; i < 8; ++i) {
        int idx = lane + i * 64;
        int rl = idx >> 4, c = idx & 15;
        int4 v = *(int4*)(E + ((rl * 256 + c * 16) ^ ((rl & 7) << 4)));
        int grow = row0 + w * 32 + rl;
        if (grow < N_NODES)
            *(int4*)((char*)supb + (size_t)grow * 256 + c * 16) = v;
    }
}

// ---------------------------------------------------------------------------
// Block-private partition (validated round 8): cursors in LDS, each 128B
// window written by exactly one block.
// meta = (local_row<<17) | col
// ---------------------------------------------------------------------------
__global__ __launch_bounds__(512) void k_part(const int* __restrict__ er,
                                              const int* __restrict__ ec,
                                              const float* __restrict__ ev,
                                              int2* __restrict__ tmp,
                                              int* __restrict__ counts,
                                              int* __restrict__ ocur,
                                              int4* __restrict__ ovf) {
    __shared__ int cur[NBUCK];
    const int tx = (int)threadIdx.x;
    const int g  = blockIdx.x;
    for (int i = tx; i < NBUCK; i += 512) cur[i] = 0;
    __syncthreads();

    const int base = g * EPB;
    for (int i = tx; i < EPB; i += 512) {
        int e = base + i;
        int   r = er[e];
        int   c = ec[e];
        float v = ev[e];
        int b = r >> 7;
        int p = atomicAdd(&cur[b], 1);
        if (p < CAPG) {
            tmp[(size_t)b * WSLOT + g * CAPG + p] =
                make_int2(((r & 127) << 17) | c, __float_as_int(v));
        } else {
            int o = atomicAdd(ocur, 1);
            if (o < OCAP) ovf[o] = make_int4(r, c, __float_as_int(v), 0);
        }
    }
    __syncthreads();
    for (int i = tx; i < NBUCK; i += 512) {
        int n = cur[i];
        counts[g * NBUCK + i] = (n > CAPG) ? CAPG : n;
    }
}

// ---------------------------------------------------------------------------
// Per-bucket CSR build, in-place, with (row, column-shard) counting sort.
// Ordering each row's edges by column shard (col>>14, 7 shards) makes all
// concurrent spmm waves sweep the column space together -> gathers hit a
// narrow L2-resident band instead of uniform 25.6 MB (round-10 change).
// ---------------------------------------------------------------------------
__global__ __launch_bounds__(320) void k_sort(int2* __restrict__ tmp,
                                              const int* __restrict__ counts,
                                              int2* __restrict__ rowrg,
                                              int* __restrict__ ocur,
                                              int4* __restrict__ ovf) {
    __shared__ int wn[G];
    __shared__ int wincl[G];
    __shared__ int hist[128 * 8], ex[128 * 8], cur[128 * 8];
    __shared__ int rowex[128];
    __shared__ int2 eb[EBCAP];
    const int tx = (int)threadIdx.x;
    const int b  = blockIdx.x;
    const int r0 = b << 7;

    int n = counts[tx * NBUCK + b];
    wn[tx] = n;
    wincl[tx] = n;
    for (int i = tx; i < 128 * 8; i += 320) { hist[i] = 0; cur[i] = 0; }
    __syncthreads();

    // inclusive scan over G=320 window counts
    for (int off = 1; off < G; off <<= 1) {
        int t = (tx >= off) ? wincl[tx - off] : 0;
        __syncthreads();
        wincl[tx] += t;
        __syncthreads();
    }
    const int cnt0 = wincl[G - 1];

    // stage window tx into eb
    {
        int o = wincl[tx] - wn[tx];
        const int2* win = tmp + ((size_t)b * G + tx) * CAPG;
        for (int k = 0; k < wn[tx]; ++k) {
            int idx = o + k;
            int2 t = win[k];
            if (idx < EBCAP) {
                eb[idx] = t;
            } else {
                int oo = atomicAdd(ocur, 1);
                if (oo < OCAP)
                    ovf[oo] = make_int4(r0 + (t.x >> 17), t.x & 0x1FFFF, t.y, 0);
            }
        }
    }
    __syncthreads();
    const int cnt = (cnt0 > EBCAP) ? EBCAP : cnt0;

    // histogram over (local_row, col_shard)
    for (int i = tx; i < cnt; i += 320) {
        int m = eb[i].x;
        atomicAdd(&hist[((m >> 17) << 3) + ((m & 0x1FFFF) >> 14)], 1);
    }
    __syncthreads();

    // per-row serial scan of 8 shards; row totals into rowex
    int rt = 0;
    if (tx < 128) {
        int s = 0;
        #pragma unroll
        for (int k = 0; k < 8; ++k) {
            int h = hist[(tx << 3) + k];
            ex[(tx << 3) + k] = s;
            s += h;
        }
        rt = s;
        rowex[tx] = s;
    }
    __syncthreads();

    // inclusive scan over 128 row totals (all threads hit barriers)
    for (int off = 1; off < 128; off <<= 1) {
        int t = 0;
        if (tx < 128 && tx >= off) t = rowex[tx - off];
        __syncthreads();
        if (tx < 128) rowex[tx] += t;
        __syncthreads();
    }
    if (tx < 128) {
        int incl = rowex[tx];
        int e0   = incl - rt;
        if (r0 + tx < N_NODES)
            rowrg[r0 + tx] = make_int2(b * WSLOT + e0, b * WSLOT + incl);
        #pragma unroll
        for (int k = 0; k < 8; ++k) ex[(tx << 3) + k] += e0;
    }
    __syncthreads();

    // place (source fully staged in LDS -> safe to overwrite bucket range)
    int2* dst = tmp + (size_t)b * WSLOT;
    for (int i = tx; i < cnt; i += 320) {
        int2 t = eb[i];
        int c   = t.x & 0x1FFFF;
        int key = ((t.x >> 17) << 3) + (c >> 14);
        int p   = ex[key] + atomicAdd(&cur[key], 1);
        dst[p] = make_int2(c, t.y);
    }
}

// ---------------------------------------------------------------------------
// CSR SpMM: one wave per row; half-wave per edge; 8 edges/iter; fold via
// __shfl_xor(32); float4 store with bias. (validated round 8, unchanged)
// ---------------------------------------------------------------------------
__global__ __launch_bounds__(256) void k_spmm(const ushort* __restrict__ supb,
                                              const int2* __restrict__ rowrg,
                                              const int2* __restrict__ scv,
                                              const float* __restrict__ bias,
                                              float* __restrict__ out) {
    const int row = blockIdx.x * 4 + (threadIdx.x >> 6);
    if (row >= N_NODES) return;
    const int lane = threadIdx.x & 63;
    const int sub  = lane >> 5;
    const int sl   = lane & 31;

    const int2 rg = rowrg[row];
    int j = rg.x;
    const int end = rg.y;
    const uint2* S = (const uint2*)supb;

    float4 acc = make_float4(0.f, 0.f, 0.f, 0.f);

    for (; j + 7 < end; j += 8) {
        int2 e0 = scv[j + sub];
        int2 e1 = scv[j + 2 + sub];
        int2 e2 = scv[j + 4 + sub];
        int2 e3 = scv[j + 6 + sub];
        uint2 s0 = S[(size_t)e0.x * 32 + sl];
        uint2 s1 = S[(size_t)e1.x * 32 + sl];
        uint2 s2 = S[(size_t)e2.x * 32 + sl];
        uint2 s3 = S[(size_t)e3.x * 32 + sl];
        float v0 = __int_as_float(e0.y), v1 = __int_as_float(e1.y);
        float v2 = __int_as_float(e2.y), v3 = __int_as_float(e3.y);
        acc.x += v0 * bflo(s0.x) + v1 * bflo(s1.x) + v2 * bflo(s2.x) + v3 * bflo(s3.x);
        acc.y += v0 * bfhi(s0.x) + v1 * bfhi(s1.x) + v2 * bfhi(s2.x) + v3 * bfhi(s3.x);
        acc.z += v0 * bflo(s0.y) + v1 * bflo(s1.y) + v2 * bflo(s2.y) + v3 * bflo(s3.y);
        acc.w += v0 * bfhi(s0.y) + v1 * bfhi(s1.y) + v2 * bfhi(s2.y) + v3 * bfhi(s3.y);
    }
    for (; j < end; j += 2) {
        int jj = j + sub;
        if (jj > end - 1) jj = end - 1;
        int2 e = scv[jj];
        float v = (j + sub < end) ? __int_as_float(e.y) : 0.f;
        uint2 s = S[(size_t)e.x * 32 + sl];
        acc.x += v * bflo(s.x);
        acc.y += v * bfhi(s.x);
        acc.z += v * bflo(s.y);
        acc.w += v * bfhi(s.y);
    }

    acc.x += __shfl_xor(acc.x, 32);
    acc.y += __shfl_xor(acc.y, 32);
    acc.z += __shfl_xor(acc.z, 32);
    acc.w += __shfl_xor(acc.w, 32);

    if (sub == 0) {
        float4 bb = *(const float4*)(bias + 4 * sl);
        acc.x += bb.x; acc.y += bb.y; acc.z += bb.z; acc.w += bb.w;
        *(float4*)(out + (size_t)row * D + 4 * sl) = acc;
    }
}

// ---------------------------------------------------------------------------
// Overflow cleanup (statistically ~100 edges): global atomics after k_spmm.
// ---------------------------------------------------------------------------
__global__ __launch_bounds__(256) void k_ofl(const ushort* __restrict__ supb,
                                             const int4* __restrict__ ovf,
                                             const int* __restrict__ ocur,
                                             float* __restrict__ out) {
    int n = *ocur;
    if (n > OCAP) n = OCAP;
    const int lane = threadIdx.x & 63;
    const uint* S = (const uint*)supb;
    for (int e = (blockIdx.x * 256 + threadIdx.x) >> 6; e < n; e += 64) {
        int4 rec = ovf[e];
        uint s = S[(size_t)rec.y * 64 + lane];
        float v = __int_as_float(rec.z);
        atomicAdd(&out[(size_t)rec.x * D + 2 * lane],     v * bflo(s));
        atomicAdd(&out[(size_t)rec.x * D + 2 * lane + 1], v * bfhi(s));
    }
}

extern "C" void kernel_launch(void* const* d_in, const int* in_sizes, int n_in,
                              void* d_out, int out_size, void* d_ws, size_t ws_size,
                              hipStream_t stream) {
    const float* x    = (const float*)d_in[0];
    const float* w    = (const float*)d_in[1];
    const float* bias = (const float*)d_in[2];
    const float* ev   = (const float*)d_in[3];
    const int*   er   = (const int*)d_in[4];
    const int*   ec   = (const int*)d_in[5];
    float* out = (float*)d_out;

    // workspace layout (16B aligned), ~59.6 MB
    char* ws = (char*)d_ws;
    ushort* supb   = (ushort*)(ws);                 // 25,600,000
    ushort* wt     = (ushort*)(ws + 25600000);      //     32,768
    int*    counts = (int*)   (ws + 25632768);      //  1,000,960
    int*    ocur   = (int*)   (ws + 26633728);      //         64
    int4*   ovf    = (int4*)  (ws + 26633792);      //    131,072
    int2*   tmp    = (int2*)  (ws + 26764864);      // 32,030,720
    int2*   rowrg  = (int2*)  (ws + 58795584);      //    800,000

    k_wt  <<<64, 256, 0, stream>>>(w, wt, ocur);
    k_gemm<<<(N_NODES + 127) / 128, 256, 0, stream>>>(x, wt, supb);

    k_part<<<G, 512, 0, stream>>>(er, ec, ev, tmp, counts, ocur, ovf);
    k_sort<<<NBUCK, 320, 0, stream>>>(tmp, counts, rowrg, ocur, ovf);

    k_spmm<<<(N_NODES + 3) / 4, 256, 0, stream>>>(supb, rowrg, tmp, bias, out);
    k_ofl <<<16, 256, 0, stream>>>(supb, ovf, ocur, out);
}

// Round 11
// 140.461 us; speedup vs baseline: 1.3224x; 1.0259x over previous
//
#include <hip/hip_runtime.h>
#include <hip/hip_bf16.h>

#define N_NODES 100000
#define N_EDGES 1600000
#define D 128
#define NBUCK 782        // ceil(100000/128) buckets of 128 rows
#define G 320            // partition blocks
#define EPB 5000         // edges per partition block (320*5000 = 1.6M)
#define CAPG 16          // slots per (bucket, block) window = 128B, line-aligned
#define WSLOT (G * CAPG) // 5120 slots per bucket in tmp
#define EBCAP 2816       // LDS staging capacity in k_sort
#define OCAP 8192        // overflow capacity

typedef short  s8v  __attribute__((ext_vector_type(8)));
typedef float  f4v  __attribute__((ext_vector_type(4)));

__device__ __forceinline__ ushort f2bf(float f) {
    uint u = __float_as_uint(f);
    return (ushort)((u + 0x7FFFu + ((u >> 16) & 1u)) >> 16);
}
__device__ __forceinline__ float bflo(uint u) { return __uint_as_float(u << 16); }
__device__ __forceinline__ float bfhi(uint u) { return __uint_as_float(u & 0xFFFF0000u); }

// ---------------------------------------------------------------------------
// wt[n][k] = bf16(w[k][n]); zeroes overflow cursor
// ---------------------------------------------------------------------------
__global__ __launch_bounds__(256) void k_wt(const float* __restrict__ w,
                                            ushort* __restrict__ wt,
                                            int* __restrict__ ocur) {
    int i = blockIdx.x * 256 + threadIdx.x;
    if (i == 0) *ocur = 0;
    if (i < D * D) {
        int k = i >> 7, n = i & 127;
        wt[n * D + k] = f2bf(w[i]);
    }
}

// ---------------------------------------------------------------------------
// supb = bf16( X @ W )  via MFMA 16x16x32 bf16.
// launch_bounds(256,4): cap VGPR at 128 -> 4 blocks/CU (16 waves/CU) for
// better A-load latency hiding (round-11 change; was (256,2) ~2 blocks/CU).
// ---------------------------------------------------------------------------
__global__ __launch_bounds__(256, 4) void k_gemm(const float* __restrict__ x,
                                                 const ushort* __restrict__ wt,
                                                 ushort* __restrict__ supb) {
    __shared__ int4 Bl4[2048];            // 32 KB
    char* Bl = (char*)Bl4;

    const int t    = threadIdx.x;
    const int lane = t & 63;
    const int w    = t >> 6;
    const int row0 = blockIdx.x * 128;

    const int4* g = (const int4*)wt;
    #pragma unroll
    for (int i = 0; i < 8; ++i) {
        int idx = t + i * 256;
        int n = idx >> 4, c = idx & 15;
        *(int4*)(Bl + ((n * 256 + c * 16) ^ ((n & 7) << 4))) = g[idx];
    }
    __syncthreads();

    f4v acc[2][8] = {};
    const int arow = row0 + w * 32 + (lane & 15);
    const int kb   = (lane >> 4) * 8;

    #pragma unroll
    for (int ks = 0; ks < 4; ++ks) {
        s8v a[2];
        #pragma unroll
        for (int m = 0; m < 2; ++m) {
            int r = arow + m * 16;
            float4 f0 = make_float4(0.f, 0.f, 0.f, 0.f);
            float4 f1 = make_float4(0.f, 0.f, 0.f, 0.f);
            if (r < N_NODES) {
                const float4* p = (const float4*)(x + (size_t)r * D + ks * 32 + kb);
                f0 = p[0];
                f1 = p[1];
            }
            s8v av;
            av[0] = (short)f2bf(f0.x); av[1] = (short)f2bf(f0.y);
            av[2] = (short)f2bf(f0.z); av[3] = (short)f2bf(f0.w);
            av[4] = (short)f2bf(f1.x); av[5] = (short)f2bf(f1.y);
            av[6] = (short)f2bf(f1.z); av[7] = (short)f2bf(f1.w);
            a[m] = av;
        }
        #pragma unroll
        for (int n = 0; n < 8; ++n) {
            int brow = n * 16 + (lane & 15);
            s8v b = *(s8v*)(Bl + ((brow * 256 + (ks * 32 + kb) * 2) ^ ((brow & 7) << 4)));
            acc[0][n] = __builtin_amdgcn_mfma_f32_16x16x32_bf16(a[0], b, acc[0][n], 0, 0, 0);
            acc[1][n] = __builtin_amdgcn_mfma_f32_16x16x32_bf16(a[1], b, acc[1][n], 0, 0, 0);
        }
    }

    __syncthreads();
    char* E = Bl + w * 8192;
    #pragma unroll
    for (int m = 0; m < 2; ++m)
        #pragma unroll
        for (int n = 0; n < 8; ++n)
            #pragma unroll
            for (int r = 0; r < 4; ++r) {
                int rl  = m * 16 + ((lane >> 4) << 2) + r;
                int col = n * 16 + (lane & 15);
                *(ushort*)(E + ((rl * 256 + col * 2) ^ ((rl & 7) << 4))) =
                    f2bf(acc[m][n][r]);
            }
    __syncthreads();
    #pragma unroll
    for (int i = 0; i < 8; ++i) {
        int idx = lane + i * 64;
        int rl = idx >> 4, c = idx & 15;
        int4 v = *(int4*)(E + ((rl * 256 + c * 16) ^ ((rl & 7) << 4)));
        int grow = row0 + w * 32 + rl;
        if (grow < N_NODES)
            *(int4*)((char*)supb + (size_t)grow * 256 + c * 16) = v;
    }
}

// ---------------------------------------------------------------------------
// Block-private partition (validated round 8): cursors in LDS, each 128B
// window written by exactly one block.  meta = (local_row<<17) | col
// ---------------------------------------------------------------------------
__global__ __launch_bounds__(512) void k_part(const int* __restrict__ er,
                                              const int* __restrict__ ec,
                                              const float* __restrict__ ev,
                                              int2* __restrict__ tmp,
                                              int* __restrict__ counts,
                                              int* __restrict__ ocur,
                                              int4* __restrict__ ovf) {
    __shared__ int cur[NBUCK];
    const int tx = (int)threadIdx.x;
    const int g  = blockIdx.x;
    for (int i = tx; i < NBUCK; i += 512) cur[i] = 0;
    __syncthreads();

    const int base = g * EPB;
    for (int i = tx; i < EPB; i += 512) {
        int e = base + i;
        int   r = er[e];
        int   c = ec[e];
        float v = ev[e];
        int b = r >> 7;
        int p = atomicAdd(&cur[b], 1);
        if (p < CAPG) {
            tmp[(size_t)b * WSLOT + g * CAPG + p] =
                make_int2(((r & 127) << 17) | c, __float_as_int(v));
        } else {
            int o = atomicAdd(ocur, 1);
            if (o < OCAP) ovf[o] = make_int4(r, c, __float_as_int(v), 0);
        }
    }
    __syncthreads();
    for (int i = tx; i < NBUCK; i += 512) {
        int n = cur[i];
        counts[g * NBUCK + i] = (n > CAPG) ? CAPG : n;
    }
}

// ---------------------------------------------------------------------------
// Per-bucket CSR build, in-place (round-8 version, shard-sort reverted):
// stage windows into LDS, row histogram + scan, place back into tmp's own
// bucket range, emit per-row (start,end).
// ---------------------------------------------------------------------------
__global__ __launch_bounds__(320) void k_sort(int2* __restrict__ tmp,
                                              const int* __restrict__ counts,
                                              int2* __restrict__ rowrg,
                                              int* __restrict__ ocur,
                                              int4* __restrict__ ovf) {
    __shared__ int wn[G];
    __shared__ int wincl[G];
    __shared__ int hist[128], ex[128], cur[128];
    __shared__ int2 eb[EBCAP];
    const int tx = (int)threadIdx.x;
    const int b  = blockIdx.x;
    const int r0 = b << 7;

    int n = counts[tx * NBUCK + b];
    wn[tx] = n;
    wincl[tx] = n;
    if (tx < 128) { hist[tx] = 0; cur[tx] = 0; }
    __syncthreads();

    // inclusive scan over G=320 window counts
    for (int off = 1; off < G; off <<= 1) {
        int t = (tx >= off) ? wincl[tx - off] : 0;
        __syncthreads();
        wincl[tx] += t;
        __syncthreads();
    }
    const int cnt0 = wincl[G - 1];

    // stage window tx into eb
    {
        int o = wincl[tx] - wn[tx];
        const int2* win = tmp + ((size_t)b * G + tx) * CAPG;
        for (int k = 0; k < wn[tx]; ++k) {
            int idx = o + k;
            int2 t = win[k];
            if (idx < EBCAP) {
                eb[idx] = t;
            } else {
                int oo = atomicAdd(ocur, 1);
                if (oo < OCAP)
                    ovf[oo] = make_int4(r0 + (t.x >> 17), t.x & 0x1FFFF, t.y, 0);
            }
        }
    }
    __syncthreads();
    const int cnt = (cnt0 > EBCAP) ? EBCAP : cnt0;

    // histogram of local rows
    for (int i = tx; i < cnt; i += 320)
        atomicAdd(&hist[eb[i].x >> 17], 1);
    __syncthreads();

    // inclusive scan over 128 (all threads hit barriers)
    int hv = (tx < 128) ? hist[tx] : 0;
    if (tx < 128) ex[tx] = hv;
    __syncthreads();
    for (int off = 1; off < 128; off <<= 1) {
        int t = 0;
        if (tx < 128 && tx >= off) t = ex[tx - off];
        __syncthreads();
        if (tx < 128) ex[tx] += t;
        __syncthreads();
    }
    if (tx < 128) {
        int incl = ex[tx];
        int e0   = incl - hv;
        if (r0 + tx < N_NODES)
            rowrg[r0 + tx] = make_int2(b * WSLOT + e0, b * WSLOT + incl);
        ex[tx] = e0;
    }
    __syncthreads();

    // place (source fully staged in LDS -> safe to overwrite bucket range)
    int2* dst = tmp + (size_t)b * WSLOT;
    for (int i = tx; i < cnt; i += 320) {
        int2 t = eb[i];
        int lr = t.x >> 17;
        int p  = ex[lr] + atomicAdd(&cur[lr], 1);
        dst[p] = make_int2(t.x & 0x1FFFF, t.y);
    }
}

// ---------------------------------------------------------------------------
// CSR SpMM: one wave per row; half-wave per edge; 8 edges/iter; fold via
// __shfl_xor(32); float4 store with bias. (validated round 8, unchanged)
// ---------------------------------------------------------------------------
__global__ __launch_bounds__(256) void k_spmm(const ushort* __restrict__ supb,
                                              const int2* __restrict__ rowrg,
                                              const int2* __restrict__ scv,
                                              const float* __restrict__ bias,
                                              float* __restrict__ out) {
    const int row = blockIdx.x * 4 + (threadIdx.x >> 6);
    if (row >= N_NODES) return;
    const int lane = threadIdx.x & 63;
    const int sub  = lane >> 5;
    const int sl   = lane & 31;

    const int2 rg = rowrg[row];
    int j = rg.x;
    const int end = rg.y;
    const uint2* S = (const uint2*)supb;

    float4 acc = make_float4(0.f, 0.f, 0.f, 0.f);

    for (; j + 7 < end; j += 8) {
        int2 e0 = scv[j + sub];
        int2 e1 = scv[j + 2 + sub];
        int2 e2 = scv[j + 4 + sub];
        int2 e3 = scv[j + 6 + sub];
        uint2 s0 = S[(size_t)e0.x * 32 + sl];
        uint2 s1 = S[(size_t)e1.x * 32 + sl];
        uint2 s2 = S[(size_t)e2.x * 32 + sl];
        uint2 s3 = S[(size_t)e3.x * 32 + sl];
        float v0 = __int_as_float(e0.y), v1 = __int_as_float(e1.y);
        float v2 = __int_as_float(e2.y), v3 = __int_as_float(e3.y);
        acc.x += v0 * bflo(s0.x) + v1 * bflo(s1.x) + v2 * bflo(s2.x) + v3 * bflo(s3.x);
        acc.y += v0 * bfhi(s0.x) + v1 * bfhi(s1.x) + v2 * bfhi(s2.x) + v3 * bfhi(s3.x);
        acc.z += v0 * bflo(s0.y) + v1 * bflo(s1.y) + v2 * bflo(s2.y) + v3 * bflo(s3.y);
        acc.w += v0 * bfhi(s0.y) + v1 * bfhi(s1.y) + v2 * bfhi(s2.y) + v3 * bfhi(s3.y);
    }
    for (; j < end; j += 2) {
        int jj = j + sub;
        if (jj > end - 1) jj = end - 1;
        int2 e = scv[jj];
        float v = (j + sub < end) ? __int_as_float(e.y) : 0.f;
        uint2 s = S[(size_t)e.x * 32 + sl];
        acc.x += v * bflo(s.x);
        acc.y += v * bfhi(s.x);
        acc.z += v * bflo(s.y);
        acc.w += v * bfhi(s.y);
    }

    acc.x += __shfl_xor(acc.x, 32);
    acc.y += __shfl_xor(acc.y, 32);
    acc.z += __shfl_xor(acc.z, 32);
    acc.w += __shfl_xor(acc.w, 32);

    if (sub == 0) {
        float4 bb = *(const float4*)(bias + 4 * sl);
        acc.x += bb.x; acc.y += bb.y; acc.z += bb.z; acc.w += bb.w;
        *(float4*)(out + (size_t)row * D + 4 * sl) = acc;
    }
}

// ---------------------------------------------------------------------------
// Overflow cleanup (statistically ~100 edges): global atomics after k_spmm.
// ---------------------------------------------------------------------------
__global__ __launch_bounds__(256) void k_ofl(const ushort* __restrict__ supb,
                                             const int4* __restrict__ ovf,
                                             const int* __restrict__ ocur,
                                             float* __restrict__ out) {
    int n = *ocur;
    if (n > OCAP) n = OCAP;
    const int lane = threadIdx.x & 63;
    const uint* S = (const uint*)supb;
    for (int e = (blockIdx.x * 256 + threadIdx.x) >> 6; e < n; e += 64) {
        int4 rec = ovf[e];
        uint s = S[(size_t)rec.y * 64 + lane];
        float v = __int_as_float(rec.z);
        atomicAdd(&out[(size_t)rec.x * D + 2 * lane],     v * bflo(s));
        atomicAdd(&out[(size_t)rec.x * D + 2 * lane + 1], v * bfhi(s));
    }
}

extern "C" void kernel_launch(void* const* d_in, const int* in_sizes, int n_in,
                              void* d_out, int out_size, void* d_ws, size_t ws_size,
                              hipStream_t stream) {
    const float* x    = (const float*)d_in[0];
    const float* w    = (const float*)d_in[1];
    const float* bias = (const float*)d_in[2];
    const float* ev   = (const float*)d_in[3];
    const int*   er   = (const int*)d_in[4];
    const int*   ec   = (const int*)d_in[5];
    float* out = (float*)d_out;

    // workspace layout (16B aligned), ~59.6 MB
    char* ws = (char*)d_ws;
    ushort* supb   = (ushort*)(ws);                 // 25,600,000
    ushort* wt     = (ushort*)(ws + 25600000);      //     32,768
    int*    counts = (int*)   (ws + 25632768);      //  1,000,960
    int*    ocur   = (int*)   (ws + 26633728);      //         64
    int4*   ovf    = (int4*)  (ws + 26633792);      //    131,072
    int2*   tmp    = (int2*)  (ws + 26764864);      // 32,030,720
    int2*   rowrg  = (int2*)  (ws + 58795584);      //    800,000

    k_wt  <<<64, 256, 0, stream>>>(w, wt, ocur);
    k_gemm<<<(N_NODES + 127) / 128, 256, 0, stream>>>(x, wt, supb);

    k_part<<<G, 512, 0, stream>>>(er, ec, ev, tmp, counts, ocur, ovf);
    k_sort<<<NBUCK, 320, 0, stream>>>(tmp, counts, rowrg, ocur, ovf);

    k_spmm<<<(N_NODES + 3) / 4, 256, 0, stream>>>(supb, rowrg, tmp, bias, out);
    k_ofl <<<16, 256, 0, stream>>>(supb, ovf, ocur, out);
}

// Round 12
// 135.832 us; speedup vs baseline: 1.3675x; 1.0341x over previous
//
#include <hip/hip_runtime.h>
#include <hip/hip_bf16.h>

#define N_NODES 100000
#define N_EDGES 1600000
#define D 128
#define NBUCK 782        // ceil(100000/128) buckets of 128 rows
#define G 320            // partition block-groups
#define EPB 5000         // edges per partition group (320*5000 = 1.6M)
#define CAPG 16          // slots per (bucket, group) window = 128B, line-aligned
#define WSLOT (G * CAPG) // 5120 slots per bucket in tmp
#define EBCAP 2816       // LDS staging capacity in k_sort
#define OCAP 8192        // overflow capacity

typedef short  s8v  __attribute__((ext_vector_type(8)));
typedef float  f4v  __attribute__((ext_vector_type(4)));

__device__ __forceinline__ ushort f2bf(float f) {
    uint u = __float_as_uint(f);
    return (ushort)((u + 0x7FFFu + ((u >> 16) & 1u)) >> 16);
}
__device__ __forceinline__ float bflo(uint u) { return __uint_as_float(u << 16); }
__device__ __forceinline__ float bfhi(uint u) { return __uint_as_float(u & 0xFFFF0000u); }

// ---------------------------------------------------------------------------
// wt[n][k] = bf16(w[k][n]); zeroes overflow cursor
// ---------------------------------------------------------------------------
__global__ __launch_bounds__(256) void k_wt(const float* __restrict__ w,
                                            ushort* __restrict__ wt,
                                            int* __restrict__ ocur) {
    int i = blockIdx.x * 256 + threadIdx.x;
    if (i == 0) *ocur = 0;
    if (i < D * D) {
        int k = i >> 7, n = i & 127;
        wt[n * D + k] = f2bf(w[i]);
    }
}

// ---------------------------------------------------------------------------
// FUSED prep kernel (round-12 change): blocks 0..781 run the validated MFMA
// GEMM (supb = bf16(X@W)); blocks 782..1101 run the validated block-private
// edge partition. The two paths touch disjoint data; fusing makes them
// co-resident so the latency-bound partition hides under the GEMM.
// LDS: gemm uses all 32KB; part reuses it for its 782 cursor ints.
// ---------------------------------------------------------------------------
__global__ __launch_bounds__(256, 4) void k_fuse(const float* __restrict__ x,
                                                 const ushort* __restrict__ wt,
                                                 ushort* __restrict__ supb,
                                                 const int* __restrict__ er,
                                                 const int* __restrict__ ec,
                                                 const float* __restrict__ ev,
                                                 int2* __restrict__ tmp,
                                                 int* __restrict__ counts,
                                                 int* __restrict__ ocur,
                                                 int4* __restrict__ ovf) {
    __shared__ __attribute__((aligned(16))) char smem[32768];

    const int t = (int)threadIdx.x;

    if (blockIdx.x < NBUCK) {
        // ---------------- GEMM path (validated rounds 3/5/7/8/11) ----------
        char* Bl = smem;
        const int lane = t & 63;
        const int w    = t >> 6;
        const int row0 = blockIdx.x * 128;

        const int4* g4 = (const int4*)wt;
        #pragma unroll
        for (int i = 0; i < 8; ++i) {
            int idx = t + i * 256;
            int n = idx >> 4, c = idx & 15;
            *(int4*)(Bl + ((n * 256 + c * 16) ^ ((n & 7) << 4))) = g4[idx];
        }
        __syncthreads();

        f4v acc[2][8] = {};
        const int arow = row0 + w * 32 + (lane & 15);
        const int kb   = (lane >> 4) * 8;

        #pragma unroll
        for (int ks = 0; ks < 4; ++ks) {
            s8v a[2];
            #pragma unroll
            for (int m = 0; m < 2; ++m) {
                int r = arow + m * 16;
                float4 f0 = make_float4(0.f, 0.f, 0.f, 0.f);
                float4 f1 = make_float4(0.f, 0.f, 0.f, 0.f);
                if (r < N_NODES) {
                    const float4* p = (const float4*)(x + (size_t)r * D + ks * 32 + kb);
                    f0 = p[0];
                    f1 = p[1];
                }
                s8v av;
                av[0] = (short)f2bf(f0.x); av[1] = (short)f2bf(f0.y);
                av[2] = (short)f2bf(f0.z); av[3] = (short)f2bf(f0.w);
                av[4] = (short)f2bf(f1.x); av[5] = (short)f2bf(f1.y);
                av[6] = (short)f2bf(f1.z); av[7] = (short)f2bf(f1.w);
                a[m] = av;
            }
            #pragma unroll
            for (int n = 0; n < 8; ++n) {
                int brow = n * 16 + (lane & 15);
                s8v b = *(s8v*)(Bl + ((brow * 256 + (ks * 32 + kb) * 2) ^ ((brow & 7) << 4)));
                acc[0][n] = __builtin_amdgcn_mfma_f32_16x16x32_bf16(a[0], b, acc[0][n], 0, 0, 0);
                acc[1][n] = __builtin_amdgcn_mfma_f32_16x16x32_bf16(a[1], b, acc[1][n], 0, 0, 0);
            }
        }

        __syncthreads();
        char* E = Bl + w * 8192;
        #pragma unroll
        for (int m = 0; m < 2; ++m)
            #pragma unroll
            for (int n = 0; n < 8; ++n)
                #pragma unroll
                for (int r = 0; r < 4; ++r) {
                    int rl  = m * 16 + ((lane >> 4) << 2) + r;
                    int col = n * 16 + (lane & 15);
                    *(ushort*)(E + ((rl * 256 + col * 2) ^ ((rl & 7) << 4))) =
                        f2bf(acc[m][n][r]);
                }
        __syncthreads();
        #pragma unroll
        for (int i = 0; i < 8; ++i) {
            int idx = lane + i * 64;
            int rl = idx >> 4, c = idx & 15;
            int4 v = *(int4*)(E + ((rl * 256 + c * 16) ^ ((rl & 7) << 4)));
            int grow = row0 + w * 32 + rl;
            if (grow < N_NODES)
                *(int4*)((char*)supb + (size_t)grow * 256 + c * 16) = v;
        }
    } else {
        // ---------------- partition path (validated round 8) ---------------
        int* cur = (int*)smem;
        const int g = blockIdx.x - NBUCK;       // 0..G-1
        for (int i = t; i < NBUCK; i += 256) cur[i] = 0;
        __syncthreads();

        const int base = g * EPB;
        for (int i = t; i < EPB; i += 256) {
            int e = base + i;
            int   r = er[e];
            int   c = ec[e];
            float v = ev[e];
            int b = r >> 7;
            int p = atomicAdd(&cur[b], 1);
            if (p < CAPG) {
                tmp[(size_t)b * WSLOT + g * CAPG + p] =
                    make_int2(((r & 127) << 17) | c, __float_as_int(v));
            } else {
                int o = atomicAdd(ocur, 1);
                if (o < OCAP) ovf[o] = make_int4(r, c, __float_as_int(v), 0);
            }
        }
        __syncthreads();
        for (int i = t; i < NBUCK; i += 256) {
            int n = cur[i];
            counts[g * NBUCK + i] = (n > CAPG) ? CAPG : n;
        }
    }
}

// ---------------------------------------------------------------------------
// Per-bucket CSR build, in-place (validated round 8): stage windows into LDS,
// row histogram + scan, place back into tmp's bucket range, emit (start,end).
// ---------------------------------------------------------------------------
__global__ __launch_bounds__(320) void k_sort(int2* __restrict__ tmp,
                                              const int* __restrict__ counts,
                                              int2* __restrict__ rowrg,
                                              int* __restrict__ ocur,
                                              int4* __restrict__ ovf) {
    __shared__ int wn[G];
    __shared__ int wincl[G];
    __shared__ int hist[128], ex[128], cur[128];
    __shared__ int2 eb[EBCAP];
    const int tx = (int)threadIdx.x;
    const int b  = blockIdx.x;
    const int r0 = b << 7;

    int n = counts[tx * NBUCK + b];
    wn[tx] = n;
    wincl[tx] = n;
    if (tx < 128) { hist[tx] = 0; cur[tx] = 0; }
    __syncthreads();

    for (int off = 1; off < G; off <<= 1) {
        int t = (tx >= off) ? wincl[tx - off] : 0;
        __syncthreads();
        wincl[tx] += t;
        __syncthreads();
    }
    const int cnt0 = wincl[G - 1];

    {
        int o = wincl[tx] - wn[tx];
        const int2* win = tmp + ((size_t)b * G + tx) * CAPG;
        for (int k = 0; k < wn[tx]; ++k) {
            int idx = o + k;
            int2 t = win[k];
            if (idx < EBCAP) {
                eb[idx] = t;
            } else {
                int oo = atomicAdd(ocur, 1);
                if (oo < OCAP)
                    ovf[oo] = make_int4(r0 + (t.x >> 17), t.x & 0x1FFFF, t.y, 0);
            }
        }
    }
    __syncthreads();
    const int cnt = (cnt0 > EBCAP) ? EBCAP : cnt0;

    for (int i = tx; i < cnt; i += 320)
        atomicAdd(&hist[eb[i].x >> 17], 1);
    __syncthreads();

    int hv = (tx < 128) ? hist[tx] : 0;
    if (tx < 128) ex[tx] = hv;
    __syncthreads();
    for (int off = 1; off < 128; off <<= 1) {
        int t = 0;
        if (tx < 128 && tx >= off) t = ex[tx - off];
        __syncthreads();
        if (tx < 128) ex[tx] += t;
        __syncthreads();
    }
    if (tx < 128) {
        int incl = ex[tx];
        int e0   = incl - hv;
        if (r0 + tx < N_NODES)
            rowrg[r0 + tx] = make_int2(b * WSLOT + e0, b * WSLOT + incl);
        ex[tx] = e0;
    }
    __syncthreads();

    int2* dst = tmp + (size_t)b * WSLOT;
    for (int i = tx; i < cnt; i += 320) {
        int2 t = eb[i];
        int lr = t.x >> 17;
        int p  = ex[lr] + atomicAdd(&cur[lr], 1);
        dst[p] = make_int2(t.x & 0x1FFFF, t.y);
    }
}

// ---------------------------------------------------------------------------
// CSR SpMM: one wave per row; half-wave per edge; 8 edges/iter; fold via
// __shfl_xor(32); float4 store with bias. (validated round 8, unchanged)
// ---------------------------------------------------------------------------
__global__ __launch_bounds__(256) void k_spmm(const ushort* __restrict__ supb,
                                              const int2* __restrict__ rowrg,
                                              const int2* __restrict__ scv,
                                              const float* __restrict__ bias,
                                              float* __restrict__ out) {
    const int row = blockIdx.x * 4 + (threadIdx.x >> 6);
    if (row >= N_NODES) return;
    const int lane = threadIdx.x & 63;
    const int sub  = lane >> 5;
    const int sl   = lane & 31;

    const int2 rg = rowrg[row];
    int j = rg.x;
    const int end = rg.y;
    const uint2* S = (const uint2*)supb;

    float4 acc = make_float4(0.f, 0.f, 0.f, 0.f);

    for (; j + 7 < end; j += 8) {
        int2 e0 = scv[j + sub];
        int2 e1 = scv[j + 2 + sub];
        int2 e2 = scv[j + 4 + sub];
        int2 e3 = scv[j + 6 + sub];
        uint2 s0 = S[(size_t)e0.x * 32 + sl];
        uint2 s1 = S[(size_t)e1.x * 32 + sl];
        uint2 s2 = S[(size_t)e2.x * 32 + sl];
        uint2 s3 = S[(size_t)e3.x * 32 + sl];
        float v0 = __int_as_float(e0.y), v1 = __int_as_float(e1.y);
        float v2 = __int_as_float(e2.y), v3 = __int_as_float(e3.y);
        acc.x += v0 * bflo(s0.x) + v1 * bflo(s1.x) + v2 * bflo(s2.x) + v3 * bflo(s3.x);
        acc.y += v0 * bfhi(s0.x) + v1 * bfhi(s1.x) + v2 * bfhi(s2.x) + v3 * bfhi(s3.x);
        acc.z += v0 * bflo(s0.y) + v1 * bflo(s1.y) + v2 * bflo(s2.y) + v3 * bflo(s3.y);
        acc.w += v0 * bfhi(s0.y) + v1 * bfhi(s1.y) + v2 * bfhi(s2.y) + v3 * bfhi(s3.y);
    }
    for (; j < end; j += 2) {
        int jj = j + sub;
        if (jj > end - 1) jj = end - 1;
        int2 e = scv[jj];
        float v = (j + sub < end) ? __int_as_float(e.y) : 0.f;
        uint2 s = S[(size_t)e.x * 32 + sl];
        acc.x += v * bflo(s.x);
        acc.y += v * bfhi(s.x);
        acc.z += v * bflo(s.y);
        acc.w += v * bfhi(s.y);
    }

    acc.x += __shfl_xor(acc.x, 32);
    acc.y += __shfl_xor(acc.y, 32);
    acc.z += __shfl_xor(acc.z, 32);
    acc.w += __shfl_xor(acc.w, 32);

    if (sub == 0) {
        float4 bb = *(const float4*)(bias + 4 * sl);
        acc.x += bb.x; acc.y += bb.y; acc.z += bb.z; acc.w += bb.w;
        *(float4*)(out + (size_t)row * D + 4 * sl) = acc;
    }
}

// ---------------------------------------------------------------------------
// Overflow cleanup (statistically ~100 edges): global atomics after k_spmm.
// ---------------------------------------------------------------------------
__global__ __launch_bounds__(256) void k_ofl(const ushort* __restrict__ supb,
                                             const int4* __restrict__ ovf,
                                             const int* __restrict__ ocur,
                                             float* __restrict__ out) {
    int n = *ocur;
    if (n > OCAP) n = OCAP;
    const int lane = threadIdx.x & 63;
    const uint* S = (const uint*)supb;
    for (int e = (blockIdx.x * 256 + threadIdx.x) >> 6; e < n; e += 64) {
        int4 rec = ovf[e];
        uint s = S[(size_t)rec.y * 64 + lane];
        float v = __int_as_float(rec.z);
        atomicAdd(&out[(size_t)rec.x * D + 2 * lane],     v * bflo(s));
        atomicAdd(&out[(size_t)rec.x * D + 2 * lane + 1], v * bfhi(s));
    }
}

extern "C" void kernel_launch(void* const* d_in, const int* in_sizes, int n_in,
                              void* d_out, int out_size, void* d_ws, size_t ws_size,
                              hipStream_t stream) {
    const float* x    = (const float*)d_in[0];
    const float* w    = (const float*)d_in[1];
    const float* bias = (const float*)d_in[2];
    const float* ev   = (const float*)d_in[3];
    const int*   er   = (const int*)d_in[4];
    const int*   ec   = (const int*)d_in[5];
    float* out = (float*)d_out;

    // workspace layout (16B aligned), ~59.6 MB
    char* ws = (char*)d_ws;
    ushort* supb   = (ushort*)(ws);                 // 25,600,000
    ushort* wt     = (ushort*)(ws + 25600000);      //     32,768
    int*    counts = (int*)   (ws + 25632768);      //  1,000,960
    int*    ocur   = (int*)   (ws + 26633728);      //         64
    int4*   ovf    = (int4*)  (ws + 26633792);      //    131,072
    int2*   tmp    = (int2*)  (ws + 26764864);      // 32,030,720
    int2*   rowrg  = (int2*)  (ws + 58795584);      //    800,000

    k_wt  <<<64, 256, 0, stream>>>(w, wt, ocur);
    // fused: GEMM (blocks 0..781) || edge partition (blocks 782..1101)
    k_fuse<<<NBUCK + G, 256, 0, stream>>>(x, wt, supb, er, ec, ev, tmp,
                                          counts, ocur, ovf);
    k_sort<<<NBUCK, 320, 0, stream>>>(tmp, counts, rowrg, ocur, ovf);

    k_spmm<<<(N_NODES + 3) / 4, 256, 0, stream>>>(supb, rowrg, tmp, bias, out);
    k_ofl <<<16, 256, 0, stream>>>(supb, ovf, ocur, out);
}

// Round 13
// 121.285 us; speedup vs baseline: 1.5315x; 1.1199x over previous
//
#include <hip/hip_runtime.h>
#include <hip/hip_bf16.h>

#define N_NODES 100000
#define N_EDGES 1600000
#define D 128
#define NBUCK 782        // ceil(100000/128) buckets of 128 rows
#define G 320            // partition block-groups
#define EPB 5000         // edges per partition group (320*5000 = 1.6M)
#define CAPG 16          // slots per (bucket, group) window = 128B, line-aligned
#define WSLOT (G * CAPG) // 5120 slots per bucket in tmp
#define EBC 2240         // LDS sorted-edge capacity (mean 2048 + 4.2 sigma)
#define OCAP 8192        // overflow capacity

typedef short  s8v  __attribute__((ext_vector_type(8)));
typedef float  f4v  __attribute__((ext_vector_type(4)));

__device__ __forceinline__ ushort f2bf(float f) {
    uint u = __float_as_uint(f);
    return (ushort)((u + 0x7FFFu + ((u >> 16) & 1u)) >> 16);
}
__device__ __forceinline__ float bflo(uint u) { return __uint_as_float(u << 16); }
__device__ __forceinline__ float bfhi(uint u) { return __uint_as_float(u & 0xFFFF0000u); }

// ---------------------------------------------------------------------------
// wt[n][k] = bf16(w[k][n]); zeroes overflow cursor
// ---------------------------------------------------------------------------
__global__ __launch_bounds__(256) void k_wt(const float* __restrict__ w,
                                            ushort* __restrict__ wt,
                                            int* __restrict__ ocur) {
    int i = blockIdx.x * 256 + threadIdx.x;
    if (i == 0) *ocur = 0;
    if (i < D * D) {
        int k = i >> 7, n = i & 127;
        wt[n * D + k] = f2bf(w[i]);
    }
}

// ---------------------------------------------------------------------------
// FUSED prep kernel (validated round 12): blocks 0..781 = MFMA GEMM,
// blocks 782..1101 = block-private edge partition.
// ---------------------------------------------------------------------------
__global__ __launch_bounds__(256, 4) void k_fuse(const float* __restrict__ x,
                                                 const ushort* __restrict__ wt,
                                                 ushort* __restrict__ supb,
                                                 const int* __restrict__ er,
                                                 const int* __restrict__ ec,
                                                 const float* __restrict__ ev,
                                                 int2* __restrict__ tmp,
                                                 int* __restrict__ counts,
                                                 int* __restrict__ ocur,
                                                 int4* __restrict__ ovf) {
    __shared__ __attribute__((aligned(16))) char smem[32768];

    const int t = (int)threadIdx.x;

    if (blockIdx.x < NBUCK) {
        // ---------------- GEMM path ----------------------------------------
        char* Bl = smem;
        const int lane = t & 63;
        const int w    = t >> 6;
        const int row0 = blockIdx.x * 128;

        const int4* g4 = (const int4*)wt;
        #pragma unroll
        for (int i = 0; i < 8; ++i) {
            int idx = t + i * 256;
            int n = idx >> 4, c = idx & 15;
            *(int4*)(Bl + ((n * 256 + c * 16) ^ ((n & 7) << 4))) = g4[idx];
        }
        __syncthreads();

        f4v acc[2][8] = {};
        const int arow = row0 + w * 32 + (lane & 15);
        const int kb   = (lane >> 4) * 8;

        #pragma unroll
        for (int ks = 0; ks < 4; ++ks) {
            s8v a[2];
            #pragma unroll
            for (int m = 0; m < 2; ++m) {
                int r = arow + m * 16;
                float4 f0 = make_float4(0.f, 0.f, 0.f, 0.f);
                float4 f1 = make_float4(0.f, 0.f, 0.f, 0.f);
                if (r < N_NODES) {
                    const float4* p = (const float4*)(x + (size_t)r * D + ks * 32 + kb);
                    f0 = p[0];
                    f1 = p[1];
                }
                s8v av;
                av[0] = (short)f2bf(f0.x); av[1] = (short)f2bf(f0.y);
                av[2] = (short)f2bf(f0.z); av[3] = (short)f2bf(f0.w);
                av[4] = (short)f2bf(f1.x); av[5] = (short)f2bf(f1.y);
                av[6] = (short)f2bf(f1.z); av[7] = (short)f2bf(f1.w);
                a[m] = av;
            }
            #pragma unroll
            for (int n = 0; n < 8; ++n) {
                int brow = n * 16 + (lane & 15);
                s8v b = *(s8v*)(Bl + ((brow * 256 + (ks * 32 + kb) * 2) ^ ((brow & 7) << 4)));
                acc[0][n] = __builtin_amdgcn_mfma_f32_16x16x32_bf16(a[0], b, acc[0][n], 0, 0, 0);
                acc[1][n] = __builtin_amdgcn_mfma_f32_16x16x32_bf16(a[1], b, acc[1][n], 0, 0, 0);
            }
        }

        __syncthreads();
        char* E = Bl + w * 8192;
        #pragma unroll
        for (int m = 0; m < 2; ++m)
            #pragma unroll
            for (int n = 0; n < 8; ++n)
                #pragma unroll
                for (int r = 0; r < 4; ++r) {
                    int rl  = m * 16 + ((lane >> 4) << 2) + r;
                    int col = n * 16 + (lane & 15);
                    *(ushort*)(E + ((rl * 256 + col * 2) ^ ((rl & 7) << 4))) =
                        f2bf(acc[m][n][r]);
                }
        __syncthreads();
        #pragma unroll
        for (int i = 0; i < 8; ++i) {
            int idx = lane + i * 64;
            int rl = idx >> 4, c = idx & 15;
            int4 v = *(int4*)(E + ((rl * 256 + c * 16) ^ ((rl & 7) << 4)));
            int grow = row0 + w * 32 + rl;
            if (grow < N_NODES)
                *(int4*)((char*)supb + (size_t)grow * 256 + c * 16) = v;
        }
    } else {
        // ---------------- partition path -----------------------------------
        int* cur = (int*)smem;
        const int g = blockIdx.x - NBUCK;       // 0..G-1
        for (int i = t; i < NBUCK; i += 256) cur[i] = 0;
        __syncthreads();

        const int base = g * EPB;
        for (int i = t; i < EPB; i += 256) {
            int e = base + i;
            int   r = er[e];
            int   c = ec[e];
            float v = ev[e];
            int b = r >> 7;
            int p = atomicAdd(&cur[b], 1);
            if (p < CAPG) {
                tmp[(size_t)b * WSLOT + g * CAPG + p] =
                    make_int2(((r & 127) << 17) | c, __float_as_int(v));
            } else {
                int o = atomicAdd(ocur, 1);
                if (o < OCAP) ovf[o] = make_int4(r, c, __float_as_int(v), 0);
            }
        }
        __syncthreads();
        for (int i = t; i < NBUCK; i += 256) {
            int n = cur[i];
            counts[g * NBUCK + i] = (n > CAPG) ? CAPG : n;
        }
    }
}

// ---------------------------------------------------------------------------
// MERGED sort+spmm (round-13 change): one block (512 thr) per 128-row bucket.
// Pass 1: coalesced read of the bucket's window region -> row histogram.
// Scan -> exclusive row starts. Pass 2: coalesced re-read, place edges into
// LDS es[] (sorted by row); spill past EBC to ovf. Then 8 waves x 16 rows
// run the validated half-wave / 8-deep gather spmm reading edges from LDS.
// Deletes: sorted-scv global write+read, rowrg, one kernel launch.
// ---------------------------------------------------------------------------
__global__ __launch_bounds__(512) void k_ss(const ushort* __restrict__ supb,
                                            const int2* __restrict__ tmp,
                                            const int* __restrict__ counts,
                                            const float* __restrict__ bias,
                                            float* __restrict__ out,
                                            int* __restrict__ ocur,
                                            int4* __restrict__ ovf) {
    __shared__ int wn[G];
    __shared__ int hist[128], ex[128], cur[128];
    __shared__ int2 es[EBC];
    const int tx = (int)threadIdx.x;
    const int b  = blockIdx.x;
    const int r0 = b << 7;

    for (int i = tx; i < G; i += 512) wn[i] = counts[i * NBUCK + b];
    if (tx < 128) { hist[tx] = 0; cur[tx] = 0; }
    __syncthreads();

    const int2* win = tmp + (size_t)b * WSLOT;

    // pass 1: histogram of local rows (coalesced window-region read)
    for (int i = tx; i < WSLOT; i += 512) {
        if ((i & (CAPG - 1)) < wn[i >> 4])
            atomicAdd(&hist[win[i].x >> 17], 1);
    }
    __syncthreads();

    // scan over 128 rows -> exclusive starts (all threads hit barriers)
    int hv = (tx < 128) ? hist[tx] : 0;
    if (tx < 128) ex[tx] = hv;
    __syncthreads();
    for (int off = 1; off < 128; off <<= 1) {
        int t = 0;
        if (tx < 128 && tx >= off) t = ex[tx - off];
        __syncthreads();
        if (tx < 128) ex[tx] += t;
        __syncthreads();
    }
    if (tx < 128) ex[tx] -= hv;   // inclusive -> exclusive
    __syncthreads();

    // pass 2: place into LDS es[], sorted by row; spill past EBC
    for (int i = tx; i < WSLOT; i += 512) {
        if ((i & (CAPG - 1)) < wn[i >> 4]) {
            int2 t = win[i];
            int lr = t.x >> 17;
            int p  = ex[lr] + atomicAdd(&cur[lr], 1);
            if (p < EBC) {
                es[p] = make_int2(t.x & 0x1FFFF, t.y);
            } else {
                int oo = atomicAdd(ocur, 1);
                if (oo < OCAP)
                    ovf[oo] = make_int4(r0 + lr, t.x & 0x1FFFF, t.y, 0);
            }
        }
    }
    __syncthreads();

    // spmm phase: wave w handles rows w*16 .. w*16+15
    const int w    = tx >> 6;
    const int lane = tx & 63;
    const int sub  = lane >> 5;
    const int sl   = lane & 31;
    const uint2* S = (const uint2*)supb;

    float4 bb = make_float4(0.f, 0.f, 0.f, 0.f);
    if (sub == 0) bb = *(const float4*)(bias + 4 * sl);

    for (int rr = 0; rr < 16; ++rr) {
        const int lr = w * 16 + rr;
        const int gr = r0 + lr;
        if (gr >= N_NODES) break;     // rows are ordered; wave-uniform

        int j = ex[lr];
        int end = j + hist[lr];
        if (end > EBC) end = EBC;

        float4 acc = make_float4(0.f, 0.f, 0.f, 0.f);

        for (; j + 7 < end; j += 8) {
            int2 e0 = es[j + sub];
            int2 e1 = es[j + 2 + sub];
            int2 e2 = es[j + 4 + sub];
            int2 e3 = es[j + 6 + sub];
            uint2 s0 = S[(size_t)e0.x * 32 + sl];
            uint2 s1 = S[(size_t)e1.x * 32 + sl];
            uint2 s2 = S[(size_t)e2.x * 32 + sl];
            uint2 s3 = S[(size_t)e3.x * 32 + sl];
            float v0 = __int_as_float(e0.y), v1 = __int_as_float(e1.y);
            float v2 = __int_as_float(e2.y), v3 = __int_as_float(e3.y);
            acc.x += v0 * bflo(s0.x) + v1 * bflo(s1.x) + v2 * bflo(s2.x) + v3 * bflo(s3.x);
            acc.y += v0 * bfhi(s0.x) + v1 * bfhi(s1.x) + v2 * bfhi(s2.x) + v3 * bfhi(s3.x);
            acc.z += v0 * bflo(s0.y) + v1 * bflo(s1.y) + v2 * bflo(s2.y) + v3 * bflo(s3.y);
            acc.w += v0 * bfhi(s0.y) + v1 * bfhi(s1.y) + v2 * bfhi(s2.y) + v3 * bfhi(s3.y);
        }
        for (; j < end; j += 2) {
            int jj = j + sub;
            if (jj > end - 1) jj = end - 1;
            int2 e = es[jj];
            float v = (j + sub < end) ? __int_as_float(e.y) : 0.f;
            uint2 s = S[(size_t)e.x * 32 + sl];
            acc.x += v * bflo(s.x);
            acc.y += v * bfhi(s.x);
            acc.z += v * bflo(s.y);
            acc.w += v * bfhi(s.y);
        }

        acc.x += __shfl_xor(acc.x, 32);
        acc.y += __shfl_xor(acc.y, 32);
        acc.z += __shfl_xor(acc.z, 32);
        acc.w += __shfl_xor(acc.w, 32);

        if (sub == 0) {
            float4 o = make_float4(acc.x + bb.x, acc.y + bb.y,
                                   acc.z + bb.z, acc.w + bb.w);
            *(float4*)(out + (size_t)gr * D + 4 * sl) = o;
        }
    }
}

// ---------------------------------------------------------------------------
// Overflow cleanup (statistically ~100 edges): global atomics after k_ss.
// ---------------------------------------------------------------------------
__global__ __launch_bounds__(256) void k_ofl(const ushort* __restrict__ supb,
                                             const int4* __restrict__ ovf,
                                             const int* __restrict__ ocur,
                                             float* __restrict__ out) {
    int n = *ocur;
    if (n > OCAP) n = OCAP;
    const int lane = threadIdx.x & 63;
    const uint* S = (const uint*)supb;
    for (int e = (blockIdx.x * 256 + threadIdx.x) >> 6; e < n; e += 64) {
        int4 rec = ovf[e];
        uint s = S[(size_t)rec.y * 64 + lane];
        float v = __int_as_float(rec.z);
        atomicAdd(&out[(size_t)rec.x * D + 2 * lane],     v * bflo(s));
        atomicAdd(&out[(size_t)rec.x * D + 2 * lane + 1], v * bfhi(s));
    }
}

extern "C" void kernel_launch(void* const* d_in, const int* in_sizes, int n_in,
                              void* d_out, int out_size, void* d_ws, size_t ws_size,
                              hipStream_t stream) {
    const float* x    = (const float*)d_in[0];
    const float* w    = (const float*)d_in[1];
    const float* bias = (const float*)d_in[2];
    const float* ev   = (const float*)d_in[3];
    const int*   er   = (const int*)d_in[4];
    const int*   ec   = (const int*)d_in[5];
    float* out = (float*)d_out;

    // workspace layout (16B aligned), ~58.8 MB
    char* ws = (char*)d_ws;
    ushort* supb   = (ushort*)(ws);                 // 25,600,000
    ushort* wt     = (ushort*)(ws + 25600000);      //     32,768
    int*    counts = (int*)   (ws + 25632768);      //  1,000,960
    int*    ocur   = (int*)   (ws + 26633728);      //         64
    int4*   ovf    = (int4*)  (ws + 26633792);      //    131,072
    int2*   tmp    = (int2*)  (ws + 26764864);      // 32,030,720

    k_wt  <<<64, 256, 0, stream>>>(w, wt, ocur);
    // fused: GEMM (blocks 0..781) || edge partition (blocks 782..1101)
    k_fuse<<<NBUCK + G, 256, 0, stream>>>(x, wt, supb, er, ec, ev, tmp,
                                          counts, ocur, ovf);
    // merged per-bucket sort + spmm
    k_ss  <<<NBUCK, 512, 0, stream>>>(supb, tmp, counts, bias, out, ocur, ovf);
    k_ofl <<<16, 256, 0, stream>>>(supb, ovf, ocur, out);
}